// Round 1
// baseline (855.803 us; speedup 1.0000x reference)
//
#include <hip/hip_runtime.h>
#include <math.h>

#define NB 100      // neighbors
#define NF 13       // features per neighbor
#define IPB 4       // items (batch elems) per block: 4 waves x 1 item

// One Jacobi rotation zeroing S[P][Q]; accumulates right-vectors in V (V = V*J).
template<int P, int Q, int RR>
__device__ __forceinline__ void jacobi_rot(float S[3][3], float V[3][3]) {
    float apq = S[P][Q];
    if (apq != 0.0f) {                       // wave-uniform branch (lanes redundant)
        float tau = (S[Q][Q] - S[P][P]) / (2.0f * apq);
        float t   = (tau >= 0.0f ? 1.0f : -1.0f) / (fabsf(tau) + sqrtf(1.0f + tau * tau));
        float c   = 1.0f / sqrtf(1.0f + t * t);
        float s   = t * c;
        S[P][P] -= t * apq;
        S[Q][Q] += t * apq;
        S[P][Q] = 0.0f; S[Q][P] = 0.0f;
        float spr = S[P][RR], sqr = S[Q][RR];
        S[P][RR] = S[RR][P] = c * spr - s * sqr;
        S[Q][RR] = S[RR][Q] = s * spr + c * sqr;
        #pragma unroll
        for (int i = 0; i < 3; ++i) {
            float vip = V[i][P], viq = V[i][Q];
            V[i][P] = c * vip - s * viq;
            V[i][Q] = s * vip + c * viq;
        }
    }
}

__device__ __forceinline__ void cross3(const float a[3], const float b[3], float o[3]) {
    o[0] = a[1] * b[2] - a[2] * b[1];
    o[1] = a[2] * b[0] - a[0] * b[2];
    o[2] = a[0] * b[1] - a[1] * b[0];
}

#define CSWAP(ea, va, eb, vb)                                                  \
    if (eb > ea) {                                                             \
        float t_;                                                              \
        t_ = ea; ea = eb; eb = t_;                                             \
        t_ = va[0]; va[0] = vb[0]; vb[0] = t_;                                 \
        t_ = va[1]; va[1] = vb[1]; vb[1] = t_;                                 \
        t_ = va[2]; va[2] = vb[2]; vb[2] = t_;                                 \
    }

__global__ __launch_bounds__(256) void svd_align_kernel(
    const float* __restrict__ net, const float* __restrict__ pa,
    const float* __restrict__ pb,  const float* __restrict__ pos,
    float* __restrict__ out, int B)
{
    __shared__ float lds[IPB * NB * NF];   // 4 * 1300 floats = 20.8 KB
    const int tid   = threadIdx.x;
    const int wave  = tid >> 6;
    const int lane  = tid & 63;
    const int item0 = blockIdx.x * IPB;
    const int nItems = min(IPB, B - item0);

    // ---- coalesced global -> LDS staging (float4) ----
    {
        const float4* src = reinterpret_cast<const float4*>(net + (size_t)item0 * (NB * NF));
        float4* dst = reinterpret_cast<float4*>(lds);
        const int nF4 = nItems * (NB * NF / 4);   // 325 per item
        for (int i = tid; i < nF4; i += 256) dst[i] = src[i];
    }
    __syncthreads();

    const int  bid    = item0 + wave;
    const bool active = (wave < nItems);
    float* my = lds + wave * (NB * NF);

    const float A  = pa[0];
    const float Bb = pb[0];
    const float OS = pos[0];

    // ---- per-lane accumulation over its neighbors ----
    float sw = 0.0f;
    float swv1[3] = {0, 0, 0}, swv2[3] = {0, 0, 0};
    float M[3][3] = {{0, 0, 0}, {0, 0, 0}, {0, 0, 0}};
    float x2s[2][3] = {{0, 0, 0}, {0, 0, 0}};
    float n2s[2][3] = {{0, 0, 0}, {0, 0, 0}};

    #pragma unroll
    for (int r = 0; r < 2; ++r) {
        int n = lane + 64 * r;
        if (active && n < NB) {
            const float* p = my + n * NF;
            float w  = fmaxf(A * p[0] + Bb, 0.0f) + 1e-8f;
            float v1[3], v2[3];
            v1[0] = p[1] + OS * p[7];
            v1[1] = p[2] + OS * p[8];
            v1[2] = p[3] + OS * p[9];
            v2[0] = p[4] + OS * p[10];
            v2[1] = p[5] + OS * p[11];
            v2[2] = p[6] + OS * p[12];
            #pragma unroll
            for (int i = 0; i < 3; ++i) { x2s[r][i] = p[4 + i]; n2s[r][i] = p[10 + i]; }
            sw += w;
            #pragma unroll
            for (int k = 0; k < 3; ++k) {
                swv1[k] += w * v1[k];
                swv2[k] += w * v2[k];
                #pragma unroll
                for (int j = 0; j < 3; ++j) M[k][j] += (w * v2[k]) * v1[j];
            }
        }
    }

    // ---- butterfly reduction over the 64-lane wave (16 values) ----
    #pragma unroll
    for (int off = 32; off >= 1; off >>= 1) {
        sw += __shfl_xor(sw, off, 64);
        #pragma unroll
        for (int k = 0; k < 3; ++k) {
            swv1[k] += __shfl_xor(swv1[k], off, 64);
            swv2[k] += __shfl_xor(swv2[k], off, 64);
            #pragma unroll
            for (int j = 0; j < 3; ++j) M[k][j] += __shfl_xor(M[k][j], off, 64);
        }
    }

    if (active) {
        // ---- covariance: cov = sum(w v2 v1^T) - sw * v2c v1c^T ----
        float inv_sw = 1.0f / sw;
        float v1c[3], v2c[3];
        #pragma unroll
        for (int i = 0; i < 3; ++i) { v1c[i] = swv1[i] * inv_sw; v2c[i] = swv2[i] * inv_sw; }
        float C[3][3];
        #pragma unroll
        for (int k = 0; k < 3; ++k)
            #pragma unroll
            for (int j = 0; j < 3; ++j) C[k][j] = M[k][j] - sw * v2c[k] * v1c[j];

        // ---- S = C^T C, Jacobi eigendecomposition -> right singular vectors ----
        float S[3][3];
        #pragma unroll
        for (int i = 0; i < 3; ++i)
            #pragma unroll
            for (int j = 0; j < 3; ++j)
                S[i][j] = C[0][i] * C[0][j] + C[1][i] * C[1][j] + C[2][i] * C[2][j];
        float V[3][3] = {{1, 0, 0}, {0, 1, 0}, {0, 0, 1}};
        #pragma unroll
        for (int sweep = 0; sweep < 6; ++sweep) {
            jacobi_rot<0, 1, 2>(S, V);
            jacobi_rot<0, 2, 1>(S, V);
            jacobi_rot<1, 2, 0>(S, V);
        }

        // columns of V + eigenvalues, sort descending
        float e0 = S[0][0], e1 = S[1][1], e2 = S[2][2];
        float vc0[3] = {V[0][0], V[1][0], V[2][0]};
        float vc1[3] = {V[0][1], V[1][1], V[2][1]};
        float vc2[3] = {V[0][2], V[1][2], V[2][2]};
        CSWAP(e0, vc0, e1, vc1);
        CSWAP(e1, vc1, e2, vc2);
        CSWAP(e0, vc0, e1, vc1);

        // ---- left singular vectors (top-2) + reflection-free Kabsch R ----
        float a0[3], a1[3];
        #pragma unroll
        for (int i = 0; i < 3; ++i)
            a0[i] = C[i][0] * vc0[0] + C[i][1] * vc0[1] + C[i][2] * vc0[2];
        #pragma unroll
        for (int i = 0; i < 3; ++i)
            a1[i] = C[i][0] * vc1[0] + C[i][1] * vc1[1] + C[i][2] * vc1[2];

        float inv0 = 1.0f / sqrtf(a0[0] * a0[0] + a0[1] * a0[1] + a0[2] * a0[2] + 1e-30f);
        float u0[3] = {a0[0] * inv0, a0[1] * inv0, a0[2] * inv0};
        float d01 = u0[0] * a1[0] + u0[1] * a1[1] + u0[2] * a1[2];
        #pragma unroll
        for (int i = 0; i < 3; ++i) a1[i] -= d01 * u0[i];
        float inv1 = 1.0f / sqrtf(a1[0] * a1[0] + a1[1] * a1[1] + a1[2] * a1[2] + 1e-30f);
        float u1[3] = {a1[0] * inv1, a1[1] * inv1, a1[2] * inv1};
        float u2[3], w2[3];
        cross3(u0, u1, u2);
        cross3(vc0, vc1, w2);   // right-handed replacement for vc2

        // R = vc0 u0^T + vc1 u1^T + w2 u2^T  (== V diag(1,1,det(VU^T)) U^T)
        float R_[3][3];
        #pragma unroll
        for (int i = 0; i < 3; ++i)
            #pragma unroll
            for (int k = 0; k < 3; ++k)
                R_[i][k] = vc0[i] * u0[k] + vc1[i] * u1[k] + w2[i] * u2[k];

        float t3[3];
        #pragma unroll
        for (int i = 0; i < 3; ++i)
            t3[i] = v1c[i] - (R_[i][0] * v2c[0] + R_[i][1] * v2c[1] + R_[i][2] * v2c[2]);

        // ---- per-neighbor outputs -> LDS (reuse this wave's staging region) ----
        #pragma unroll
        for (int r = 0; r < 2; ++r) {
            int n = lane + 64 * r;
            if (n < NB) {
                float* q = my + n * 6;
                #pragma unroll
                for (int i = 0; i < 3; ++i) {
                    q[i] = R_[i][0] * x2s[r][0] + R_[i][1] * x2s[r][1] +
                           R_[i][2] * x2s[r][2] + t3[i];
                    q[3 + i] = R_[i][0] * n2s[r][0] + R_[i][1] * n2s[r][1] +
                               R_[i][2] * n2s[r][2];
                }
            }
        }
    }
    __syncthreads();

    // ---- coalesced LDS -> global store (600 floats/item = 150 float4) ----
    if (active) {
        float4* gdst = reinterpret_cast<float4*>(out + (size_t)bid * (NB * 6));
        const float4* lsrc = reinterpret_cast<const float4*>(my);
        for (int i = lane; i < (NB * 6 / 4); i += 64) gdst[i] = lsrc[i];
    }
}

extern "C" void kernel_launch(void* const* d_in, const int* in_sizes, int n_in,
                              void* d_out, int out_size, void* d_ws, size_t ws_size,
                              hipStream_t stream) {
    (void)n_in; (void)out_size; (void)d_ws; (void)ws_size;
    const float* net = (const float*)d_in[0];
    const float* pa  = (const float*)d_in[1];
    const float* pb  = (const float*)d_in[2];
    const float* pos = (const float*)d_in[3];
    float* out = (float*)d_out;
    int B = in_sizes[0] / (NB * NF);
    int grid = (B + IPB - 1) / IPB;
    svd_align_kernel<<<grid, 256, 0, stream>>>(net, pa, pb, pos, out, B);
}

// Round 2
// 761.079 us; speedup vs baseline: 1.1245x; 1.1245x over previous
//
#include <hip/hip_runtime.h>
#include <math.h>

#define NB 100      // neighbors
#define NF 13       // features per neighbor
#define IPB 4       // items (batch elems) per block: 4 waves x 1 item

// Branchless Jacobi rotation zeroing S[P][Q]; accumulates right-vectors V = V*J.
// Fast path: raw v_rcp/v_sqrt/v_rsq (1-ulp-ish), NaN/inf-safe via one select:
//   apq==0           -> tau = inf or NaN -> t forced to 0 -> identity rotation
//   apq!=0, Spp==Sqq -> tau = 0 -> t = 1 (45 deg)  [correct]
template<int P, int Q, int RR>
__device__ __forceinline__ void jacobi_rot(float S[3][3], float V[3][3]) {
    const float apq = S[P][Q];
    const float tau = (S[Q][Q] - S[P][P]) * 0.5f * __builtin_amdgcn_rcpf(apq);
    float t = __builtin_copysignf(
        __builtin_amdgcn_rcpf(fabsf(tau) +
            __builtin_amdgcn_sqrtf(__builtin_fmaf(tau, tau, 1.0f))), tau);
    t = (apq == 0.0f) ? 0.0f : t;                    // identity if already zero
    const float c = __builtin_amdgcn_rsqf(__builtin_fmaf(t, t, 1.0f));
    const float s = t * c;
    const float ta = t * apq;
    S[P][P] -= ta;
    S[Q][Q] += ta;
    S[P][Q] = 0.0f; S[Q][P] = 0.0f;                  // already 0 when apq==0
    const float spr = S[P][RR], sqr = S[Q][RR];
    S[P][RR] = S[RR][P] = c * spr - s * sqr;
    S[Q][RR] = S[RR][Q] = s * spr + c * sqr;
    #pragma unroll
    for (int i = 0; i < 3; ++i) {
        const float vip = V[i][P], viq = V[i][Q];
        V[i][P] = c * vip - s * viq;
        V[i][Q] = s * vip + c * viq;
    }
}

__device__ __forceinline__ void cross3(const float a[3], const float b[3], float o[3]) {
    o[0] = a[1] * b[2] - a[2] * b[1];
    o[1] = a[2] * b[0] - a[0] * b[2];
    o[2] = a[0] * b[1] - a[1] * b[0];
}

// Branchless conditional swap (descending): compiles to cndmasks, no exec-mask ops.
#define CSWAP(ea, va, eb, vb)                                                  \
    {                                                                          \
        const bool sw_ = (eb > ea);                                            \
        float t_;                                                              \
        t_ = ea; ea = sw_ ? eb : ea; eb = sw_ ? t_ : eb;                       \
        t_ = va[0]; va[0] = sw_ ? vb[0] : va[0]; vb[0] = sw_ ? t_ : vb[0];     \
        t_ = va[1]; va[1] = sw_ ? vb[1] : va[1]; vb[1] = sw_ ? t_ : vb[1];     \
        t_ = va[2]; va[2] = sw_ ? vb[2] : va[2]; vb[2] = sw_ ? t_ : vb[2];     \
    }

__global__ __launch_bounds__(256) void svd_align_kernel(
    const float* __restrict__ net, const float* __restrict__ pa,
    const float* __restrict__ pb,  const float* __restrict__ pos,
    float* __restrict__ out, int B)
{
    __shared__ float lds[IPB * NB * NF];   // 4 * 1300 floats = 20.8 KB
    const int tid   = threadIdx.x;
    const int wave  = tid >> 6;
    const int lane  = tid & 63;
    const int item0 = blockIdx.x * IPB;
    const int nItems = min(IPB, B - item0);

    // ---- coalesced global -> LDS staging (float4) ----
    {
        const float4* src = reinterpret_cast<const float4*>(net + (size_t)item0 * (NB * NF));
        float4* dst = reinterpret_cast<float4*>(lds);
        const int nF4 = nItems * (NB * NF / 4);   // 325 per item
        for (int i = tid; i < nF4; i += 256) dst[i] = src[i];
    }
    __syncthreads();

    const int  bid    = item0 + wave;
    const bool active = (wave < nItems);
    float* my = lds + wave * (NB * NF);

    const float A  = pa[0];
    const float Bb = pb[0];
    const float OS = pos[0];

    // ---- per-lane accumulation over its neighbors ----
    float sw = 0.0f;
    float swv1[3] = {0, 0, 0}, swv2[3] = {0, 0, 0};
    float M[3][3] = {{0, 0, 0}, {0, 0, 0}, {0, 0, 0}};
    float x2s[2][3] = {{0, 0, 0}, {0, 0, 0}};
    float n2s[2][3] = {{0, 0, 0}, {0, 0, 0}};

    #pragma unroll
    for (int r = 0; r < 2; ++r) {
        int n = lane + 64 * r;
        if (active && n < NB) {
            const float* p = my + n * NF;
            float w  = fmaxf(__builtin_fmaf(A, p[0], Bb), 0.0f) + 1e-8f;
            float v1[3], v2[3];
            v1[0] = __builtin_fmaf(OS, p[7],  p[1]);
            v1[1] = __builtin_fmaf(OS, p[8],  p[2]);
            v1[2] = __builtin_fmaf(OS, p[9],  p[3]);
            v2[0] = __builtin_fmaf(OS, p[10], p[4]);
            v2[1] = __builtin_fmaf(OS, p[11], p[5]);
            v2[2] = __builtin_fmaf(OS, p[12], p[6]);
            #pragma unroll
            for (int i = 0; i < 3; ++i) { x2s[r][i] = p[4 + i]; n2s[r][i] = p[10 + i]; }
            sw += w;
            #pragma unroll
            for (int k = 0; k < 3; ++k) {
                swv1[k] = __builtin_fmaf(w, v1[k], swv1[k]);
                swv2[k] = __builtin_fmaf(w, v2[k], swv2[k]);
                const float wv2k = w * v2[k];
                #pragma unroll
                for (int j = 0; j < 3; ++j) M[k][j] = __builtin_fmaf(wv2k, v1[j], M[k][j]);
            }
        }
    }

    // ---- butterfly reduction over the 64-lane wave (16 values) ----
    #pragma unroll
    for (int off = 32; off >= 1; off >>= 1) {
        sw += __shfl_xor(sw, off, 64);
        #pragma unroll
        for (int k = 0; k < 3; ++k) {
            swv1[k] += __shfl_xor(swv1[k], off, 64);
            swv2[k] += __shfl_xor(swv2[k], off, 64);
            #pragma unroll
            for (int j = 0; j < 3; ++j) M[k][j] += __shfl_xor(M[k][j], off, 64);
        }
    }

    if (active) {
        // ---- covariance: cov = sum(w v2 v1^T) - sw * v2c v1c^T ----
        const float inv_sw = __builtin_amdgcn_rcpf(sw);
        float v1c[3], v2c[3];
        #pragma unroll
        for (int i = 0; i < 3; ++i) { v1c[i] = swv1[i] * inv_sw; v2c[i] = swv2[i] * inv_sw; }
        float C[3][3];
        #pragma unroll
        for (int k = 0; k < 3; ++k)
            #pragma unroll
            for (int j = 0; j < 3; ++j)
                C[k][j] = __builtin_fmaf(-sw * v2c[k], v1c[j], M[k][j]);

        // ---- S = C^T C, Jacobi eigendecomposition -> right singular vectors ----
        float S[3][3];
        #pragma unroll
        for (int i = 0; i < 3; ++i)
            #pragma unroll
            for (int j = 0; j < 3; ++j)
                S[i][j] = C[0][i] * C[0][j] + C[1][i] * C[1][j] + C[2][i] * C[2][j];
        float V[3][3] = {{1, 0, 0}, {0, 1, 0}, {0, 0, 1}};
        #pragma unroll
        for (int sweep = 0; sweep < 4; ++sweep) {    // 4 sweeps: 3x3 converges quadratically
            jacobi_rot<0, 1, 2>(S, V);
            jacobi_rot<0, 2, 1>(S, V);
            jacobi_rot<1, 2, 0>(S, V);
        }

        // columns of V + eigenvalues, sort descending (branchless)
        float e0 = S[0][0], e1 = S[1][1], e2 = S[2][2];
        float vc0[3] = {V[0][0], V[1][0], V[2][0]};
        float vc1[3] = {V[0][1], V[1][1], V[2][1]};
        float vc2[3] = {V[0][2], V[1][2], V[2][2]};
        CSWAP(e0, vc0, e1, vc1);
        CSWAP(e1, vc1, e2, vc2);
        CSWAP(e0, vc0, e1, vc1);
        (void)vc2;

        // ---- left singular vectors (top-2) + reflection-free Kabsch R ----
        float a0[3], a1[3];
        #pragma unroll
        for (int i = 0; i < 3; ++i)
            a0[i] = C[i][0] * vc0[0] + C[i][1] * vc0[1] + C[i][2] * vc0[2];
        #pragma unroll
        for (int i = 0; i < 3; ++i)
            a1[i] = C[i][0] * vc1[0] + C[i][1] * vc1[1] + C[i][2] * vc1[2];

        const float inv0 = __builtin_amdgcn_rsqf(
            a0[0] * a0[0] + a0[1] * a0[1] + a0[2] * a0[2] + 1e-30f);
        float u0[3] = {a0[0] * inv0, a0[1] * inv0, a0[2] * inv0};
        const float d01 = u0[0] * a1[0] + u0[1] * a1[1] + u0[2] * a1[2];
        #pragma unroll
        for (int i = 0; i < 3; ++i) a1[i] = __builtin_fmaf(-d01, u0[i], a1[i]);
        const float inv1 = __builtin_amdgcn_rsqf(
            a1[0] * a1[0] + a1[1] * a1[1] + a1[2] * a1[2] + 1e-30f);
        float u1[3] = {a1[0] * inv1, a1[1] * inv1, a1[2] * inv1};
        float u2[3], w2[3];
        cross3(u0, u1, u2);
        cross3(vc0, vc1, w2);   // right-handed replacement for vc2

        // R = vc0 u0^T + vc1 u1^T + w2 u2^T  (== V diag(1,1,det(VU^T)) U^T)
        float R_[3][3];
        #pragma unroll
        for (int i = 0; i < 3; ++i)
            #pragma unroll
            for (int k = 0; k < 3; ++k)
                R_[i][k] = vc0[i] * u0[k] + vc1[i] * u1[k] + w2[i] * u2[k];

        float t3[3];
        #pragma unroll
        for (int i = 0; i < 3; ++i)
            t3[i] = v1c[i] - (R_[i][0] * v2c[0] + R_[i][1] * v2c[1] + R_[i][2] * v2c[2]);

        // ---- per-neighbor outputs -> LDS (reuse this wave's staging region) ----
        #pragma unroll
        for (int r = 0; r < 2; ++r) {
            int n = lane + 64 * r;
            if (n < NB) {
                float* q = my + n * 6;
                #pragma unroll
                for (int i = 0; i < 3; ++i) {
                    q[i] = __builtin_fmaf(R_[i][0], x2s[r][0],
                           __builtin_fmaf(R_[i][1], x2s[r][1],
                           __builtin_fmaf(R_[i][2], x2s[r][2], t3[i])));
                    q[3 + i] = R_[i][0] * n2s[r][0] + R_[i][1] * n2s[r][1] +
                               R_[i][2] * n2s[r][2];
                }
            }
        }
    }
    __syncthreads();

    // ---- coalesced LDS -> global store (600 floats/item = 150 float4) ----
    if (active) {
        float4* gdst = reinterpret_cast<float4*>(out + (size_t)bid * (NB * 6));
        const float4* lsrc = reinterpret_cast<const float4*>(my);
        for (int i = lane; i < (NB * 6 / 4); i += 64) gdst[i] = lsrc[i];
    }
}

extern "C" void kernel_launch(void* const* d_in, const int* in_sizes, int n_in,
                              void* d_out, int out_size, void* d_ws, size_t ws_size,
                              hipStream_t stream) {
    (void)n_in; (void)out_size; (void)d_ws; (void)ws_size;
    const float* net = (const float*)d_in[0];
    const float* pa  = (const float*)d_in[1];
    const float* pb  = (const float*)d_in[2];
    const float* pos = (const float*)d_in[3];
    float* out = (float*)d_out;
    int B = in_sizes[0] / (NB * NF);
    int grid = (B + IPB - 1) / IPB;
    svd_align_kernel<<<grid, 256, 0, stream>>>(net, pa, pb, pos, out, B);
}